// Round 16
// baseline (395.996 us; speedup 1.0000x reference)
//
#include <hip/hip_runtime.h>

#define BS_TOK 16384
#define HD 512
#define IDIM 2048
#define NE 8
#define RT_MAX 264            // max 128-row tiles after per-expert padding
#define CAP (RT_MAX * 128)    // 33792 slots

typedef unsigned short u16;
typedef unsigned int u32;
typedef unsigned long long u64;
typedef __attribute__((ext_vector_type(8))) __bf16 bf16x8;
typedef __attribute__((ext_vector_type(4))) float f32x4;

__device__ __forceinline__ u16 f2bf(float f) {
  u32 u = __builtin_bit_cast(u32, f);
  u += 0x7fffu + ((u >> 16) & 1u);
  return (u16)(u >> 16);
}
__device__ __forceinline__ u16 f2bf_hw(float f) {
  u32 r;
  asm("v_cvt_pk_bf16_f32 %0, %1, %2" : "=v"(r) : "v"(f), "v"(f));
  return (u16)r;
}
__device__ __forceinline__ u32 pack2bf(float a, float b) {
  u32 r;
  asm("v_cvt_pk_bf16_f32 %0, %1, %2" : "=v"(r) : "v"(a), "v"(b));
  return r;
}
__device__ __forceinline__ float bflo(u32 u) { return __builtin_bit_cast(float, u << 16); }
__device__ __forceinline__ float bfhi(u32 u) { return __builtin_bit_cast(float, u & 0xffff0000u); }
// gelu tanh-approx via sigmoid; exp via v_exp_f32 (=2^x), log2e folded. Saturation-safe.
__device__ __forceinline__ float gelu_t(float v) {
  float t = v * (-2.302558f - 0.1029474f * v * v);
  return v * __builtin_amdgcn_rcpf(1.0f + __builtin_amdgcn_exp2f(t));
}
__device__ __forceinline__ void gload16(const u16* g, u16* l) {
  __builtin_amdgcn_global_load_lds((const __attribute__((address_space(1))) u16*)g,
                                   (__attribute__((address_space(3))) u16*)l, 16, 0, 0);
}

// Fused prep: blocks [0,4096) = 64x64 weight transpose (u64 coalesced stores);
// blocks [4096,8192) = router (r12-proven padded-LDS), 4 tokens/block.
__global__ void k_prep(const float* __restrict__ W1, u16* __restrict__ W1T,
                       const float* __restrict__ W2, u16* __restrict__ W2T,
                       const float* __restrict__ x, const float* __restrict__ Wg,
                       const float* __restrict__ bg, int* __restrict__ top_e,
                       float* __restrict__ top_w, u32* __restrict__ counts,
                       float* __restrict__ Psum, u16* __restrict__ xb) {
  __shared__ float t[64][65];
  __shared__ float wg_s[HD * 9];
  __shared__ float Pp[NE];
  __shared__ u32 cnt[NE];
  int bid = blockIdx.x;
  int tid = threadIdx.x;
  if (bid < 4096) {
    int z = bid >> 8, tl = bid & 255;
    const float* in; u16* out; int Rin, Cin;
    if (z < NE) { in = W1; out = W1T; Rin = HD; Cin = IDIM; }
    else { in = W2; out = W2T; Rin = IDIM; Cin = HD; z -= NE; }
    size_t eb = (size_t)z * HD * IDIM;
    int tpr = Cin >> 6;
    int r0 = (tl / tpr) << 6, c0 = (tl % tpr) << 6;
    int row = tid >> 4, c4 = (tid & 15) << 2;
    #pragma unroll
    for (int i = 0; i < 4; ++i) {
      float4 v = *(const float4*)(in + eb + (size_t)(r0 + row + i * 16) * Cin + c0 + c4);
      t[row + i * 16][c4 + 0] = v.x; t[row + i * 16][c4 + 1] = v.y;
      t[row + i * 16][c4 + 2] = v.z; t[row + i * 16][c4 + 3] = v.w;
    }
    __syncthreads();
    int cc = tid >> 4, rr = (tid & 15) << 2;
    #pragma unroll
    for (int i = 0; i < 4; ++i) {
      int c = cc + i * 16;
      u32 lo = pack2bf(t[rr + 0][c], t[rr + 1][c]);
      u32 hi = pack2bf(t[rr + 2][c], t[rr + 3][c]);
      u64 v = (u64)lo | ((u64)hi << 32);
      *(u64*)(out + eb + (size_t)(c0 + c) * Rin + r0 + rr) = v;   // 8B coalesced
    }
    return;
  }
  // ---- router ----
  if (tid < NE) { Pp[tid] = 0.f; cnt[tid] = 0; }
  for (int i = tid; i < HD * NE; i += 256) wg_s[(i >> 3) * 9 + (i & 7)] = Wg[i];
  __syncthreads();
  int wv = tid >> 6, lane = tid & 63;
  int tk = (bid - 4096) * 4 + wv;

  const float4* xr = (const float4*)(x + (size_t)tk * HD + lane * 8);
  float4 a = xr[0], b = xr[1];
  u32 p0 = pack2bf(a.x, a.y), p1 = pack2bf(a.z, a.w);
  u32 p2 = pack2bf(b.x, b.y), p3 = pack2bf(b.z, b.w);
  ((uint4*)(xb + (size_t)tk * HD))[lane] = make_uint4(p0, p1, p2, p3);

  float acc[NE];
  #pragma unroll
  for (int e = 0; e < NE; ++e) acc[e] = 0.f;
  #pragma unroll
  for (int j = 0; j < 8; ++j) {
    int h = lane + 64 * j;
    float xv = x[(size_t)tk * HD + h];
    const float* wrow = wg_s + h * 9;
    #pragma unroll
    for (int e = 0; e < NE; ++e) acc[e] += xv * wrow[e];
  }
  #pragma unroll
  for (int off = 32; off > 0; off >>= 1) {
    #pragma unroll
    for (int e = 0; e < NE; ++e) acc[e] += __shfl_down(acc[e], off);
  }
  if (lane == 0) {
    float lg[NE];
    #pragma unroll
    for (int e = 0; e < NE; ++e) lg[e] = acc[e] + bg[e];
    int i1 = 0; float m1 = lg[0];
    #pragma unroll
    for (int e = 1; e < NE; ++e) if (lg[e] > m1) { m1 = lg[e]; i1 = e; }
    int i2 = -1; float m2 = -1e30f;
    #pragma unroll
    for (int e = 0; e < NE; ++e) if (e != i1 && lg[e] > m2) { m2 = lg[e]; i2 = e; }
    float s = 0.f, p[NE];
    #pragma unroll
    for (int e = 0; e < NE; ++e) { p[e] = __expf(lg[e] - m1); s += p[e]; }
    float inv = 1.f / s;
    #pragma unroll
    for (int e = 0; e < NE; ++e) { p[e] *= inv; atomicAdd(&Pp[e], p[e]); }
    float denom = p[i1] + p[i2];
    top_e[2 * tk] = i1; top_e[2 * tk + 1] = i2;
    top_w[2 * tk] = p[i1] / denom; top_w[2 * tk + 1] = p[i2] / denom;
    atomicAdd(&cnt[i1], 1u); atomicAdd(&cnt[i2], 1u);
  }
  __syncthreads();
  if (tid < NE) { atomicAdd(&counts[tid], cnt[tid]); atomicAdd(&Psum[tid], Pp[tid]); }
}

// scatter with fused scan; perm_t stores g = (token<<1)|k; block 0 also writes
// -1 sentinels into pad slots (replaces the 0xFF memset) + padoff + loss.
__global__ void k_scatter(const int* __restrict__ top_e, const float* __restrict__ top_w,
                          const u32* __restrict__ counts, const float* __restrict__ Psum,
                          u32* __restrict__ pos_rel, int* __restrict__ perm_t,
                          u32* __restrict__ padoff, float* __restrict__ out) {
  __shared__ u32 po[NE];
  if (threadIdx.x == 0) {
    u32 off = 0; float loss = 0.f;
    for (int e = 0; e < NE; ++e) {
      po[e] = off;
      off += ((counts[e] + 127u) / 128u) * 128u;
      loss += ((float)counts[e] / (float)(BS_TOK * 2)) * (Psum[e] / (float)BS_TOK);
    }
    if (blockIdx.x == 0) {
      for (int e = 0; e < NE; ++e) padoff[e] = po[e];
      padoff[NE] = off;
      out[(size_t)BS_TOK * HD] = 0.01f * (float)NE * loss;
    }
  }
  __syncthreads();
  if (blockIdx.x == 0) {   // pad sentinels (disjoint from occupied slots)
    #pragma unroll
    for (int e = 0; e < NE; ++e) {
      u32 c = counts[e];
      u32 pc = ((c + 127u) / 128u) * 128u;
      for (u32 i = c + threadIdx.x; i < pc; i += 256) perm_t[po[e] + i] = -1;
    }
  }
  int g = blockIdx.x * 256 + threadIdx.x;   // (token,k) pair id
  int e = top_e[g];
  int lane = threadIdx.x & 63;
  #pragma unroll
  for (int ee = 0; ee < NE; ++ee) {
    unsigned long long m = __ballot(e == ee);
    if (e == ee) {
      int nb = __popcll(m & ((1ull << lane) - 1ull));
      int leader = __ffsll((unsigned long long)m) - 1;
      u32 base = 0;
      if (lane == leader) base = atomicAdd(&pos_rel[ee], (u32)__popcll(m));
      base = __shfl(base, leader);
      int slot = (int)(po[ee] + base) + nb;
      perm_t[slot] = g;
    }
  }
}

// 128x256 / BK=64 GEMM, 512 thr / 8 waves (2M x 4N, wave tile 64x64 = r12's
// per-wave workload). 3-slot LDS pipeline, ONE vmcnt(6)+s_barrier per K-step:
//   stage(ks+2 -> slot (ks+2)%3, disjoint from slots read at ks and ks+1),
//   ds_read frags (compiler-scheduled fine-grained lgkmcnt), 32 MFMA,
//   vmcnt(6) [ks+1's 6 loads landed; ks+2's stay in flight], s_barrier.
// Write-after-read: slot (ks+2)%3 last read at step ks-1, sealed by its barrier.
template <int KSTEPS, int NCT, int NTOT, bool GATHER, bool ACT, bool SCAT>
__global__ __launch_bounds__(512, 2) void k_gemm(
    const u16* __restrict__ A, int lda, const u16* __restrict__ W,
    const float* __restrict__ bias, const int* __restrict__ perm_t,
    const u32* __restrict__ padoff, u16* __restrict__ C) {
  __shared__ u16 As[3][8192];     // 3 x 16 KB  (128 rows x 64 K)
  __shared__ u16 Bs[3][16384];    // 3 x 32 KB  (256 rows x 64 K)
  int nb = gridDim.x;
  int b = blockIdx.x;
  int tile = (b & 7) * (nb >> 3) + (b >> 3);   // XCD-chunked (nb % 8 == 0)
  int rt = tile / NCT, ct = tile % NCT;
  u32 s0 = (u32)rt * 128u;
  if (s0 >= padoff[NE]) return;
  int e = 0;
  #pragma unroll
  for (int k = 1; k < NE; ++k) e += (s0 >= padoff[k]) ? 1 : 0;

  int tid = threadIdx.x;                       // 0..511
  int wv = tid >> 6, lane = tid & 63;
  int l15 = lane & 15, lg4 = lane >> 4;
  int wm = wv >> 2, wn = wv & 3;               // 2M x 4N wave grid

  int cb = (tid & 7) * 16;
  const u16* ap[2]; const u16* bp[4];
  #pragma unroll
  for (int i = 0; i < 2; ++i) {
    int row = (tid >> 3) + i * 64;
    int off = (cb ^ ((row & 7) << 4)) >> 1;    // pre-swizzled source elem offset
    int arow;
    if (GATHER) {
      int g = perm_t[s0 + row];
      arow = (g < 0 ? 0 : g) >> 1;
    } else {
      arow = (int)(s0 + row);
    }
    ap[i] = A + (size_t)arow * lda + off;
  }
  #pragma unroll
  for (int i = 0; i < 4; ++i) {
    int row = (tid >> 3) + i * 64;
    int off = (cb ^ ((row & 7) << 4)) >> 1;
    bp[i] = W + ((size_t)e * NTOT + ct * 256 + row) * (KSTEPS * 64) + off;
  }

  int base_n = ct * 256 + wn * 64;
  f32x4 acc[4][4];
  #pragma unroll
  for (int fc = 0; fc < 4; ++fc) {
    float bv = bias[(size_t)e * NTOT + base_n + fc * 16 + l15];
    #pragma unroll
    for (int fr = 0; fr < 4; ++fr) acc[fr][fc] = f32x4{bv, bv, bv, bv};
  }

  // prologue: stage K-steps 0 -> slot0, 1 -> slot1 (12 loads; 6 per K-step)
  #pragma unroll
  for (int i = 0; i < 2; ++i) gload16(ap[i], As[0] + tid * 8 + i * 4096);
  #pragma unroll
  for (int i = 0; i < 4; ++i) gload16(bp[i], Bs[0] + tid * 8 + i * 4096);
  #pragma unroll
  for (int i = 0; i < 2; ++i) gload16(ap[i] + 64, As[1] + tid * 8 + i * 4096);
  #pragma unroll
  for (int i = 0; i < 4; ++i) gload16(bp[i] + 64, Bs[1] + tid * 8 + i * 4096);
  asm volatile("s_waitcnt vmcnt(6)" ::: "memory");   // K-step 0 landed
  __builtin_amdgcn_s_barrier();
  asm volatile("" ::: "memory");

  for (int ks = 0; ks < KSTEPS; ++ks) {
    int slot = ks % 3;
    if (ks + 2 < KSTEPS) {                      // issue-early: stage ks+2
      int sl2 = (ks + 2) % 3;
      int k0 = (ks + 2) * 64;
      #pragma unroll
      for (int i = 0; i < 2; ++i) gload16(ap[i] + k0, As[sl2] + tid * 8 + i * 4096);
      #pragma unroll
      for (int i = 0; i < 4; ++i) gload16(bp[i] + k0, Bs[sl2] + tid * 8 + i * 4096);
    }
    const u16* Ab = As[slot];
    const u16* Bb = Bs[slot];
    bf16x8 af[2][4], bf[2][4];
    #pragma unroll
    for (int kk = 0; kk < 2; ++kk) {
      #pragma unroll
      for (int f = 0; f < 4; ++f) {
        int ra = wm * 64 + f * 16 + l15;
        af[kk][f] = *(const bf16x8*)((const char*)Ab +
                    (ra * 128 + ((kk * 64 + lg4 * 16) ^ ((ra & 7) << 4))));
        int rb = wn * 64 + f * 16 + l15;
        bf[kk][f] = *(const bf16x8*)((const char*)Bb +
                    (rb * 128 + ((kk * 64 + lg4 * 16) ^ ((rb & 7) << 4))));
      }
    }
    // no inline lgkmcnt: compiler emits fine-grained waits ds_read -> MFMA
    __builtin_amdgcn_s_setprio(1);
    #pragma unroll
    for (int kk = 0; kk < 2; ++kk)
      #pragma unroll
      for (int fr = 0; fr < 4; ++fr)
        #pragma unroll
        for (int fc = 0; fc < 4; ++fc)
          acc[fr][fc] = __builtin_amdgcn_mfma_f32_16x16x32_bf16(af[kk][fr], bf[kk][fc], acc[fr][fc], 0, 0, 0);
    __builtin_amdgcn_s_setprio(0);

    if (ks + 1 < KSTEPS) {
      if (ks + 2 < KSTEPS) {
        asm volatile("s_waitcnt vmcnt(6)" ::: "memory");  // ks+1 landed; ks+2 in flight
      } else {
        asm volatile("s_waitcnt vmcnt(0)" ::: "memory");  // tail drain
      }
      __builtin_amdgcn_s_barrier();
      asm volatile("" ::: "memory");
    }
  }

  #pragma unroll
  for (int fr = 0; fr < 4; ++fr) {
    u32 mrow = s0 + wm * 64 + fr * 16 + lg4 * 4;
    #pragma unroll
    for (int rr = 0; rr < 4; ++rr) {
      u32 m = mrow + rr;
      if (SCAT) {
        int g = perm_t[m];
        if (g >= 0) {
          #pragma unroll
          for (int fc = 0; fc < 4; ++fc)
            C[(size_t)g * NTOT + base_n + fc * 16 + l15] = f2bf_hw(acc[fr][fc][rr]);
        }
      } else {
        #pragma unroll
        for (int fc = 0; fc < 4; ++fc) {
          float v = acc[fr][fc][rr];          // bias already in acc
          if (ACT) v = gelu_t(v);
          C[(size_t)m * NTOT + base_n + fc * 16 + l15] = f2bf_hw(v);
        }
      }
    }
  }
}

// Fully-streaming final: out[t] = x[t] + w0*y2[2t] + w1*y2[2t+1]
__global__ void k_final(const float* __restrict__ x, const u16* __restrict__ y2,
                        const float* __restrict__ top_w, float* __restrict__ out) {
  int tid = threadIdx.x;
  int t = blockIdx.x * 4 + (tid >> 6);
  int lane = tid & 63;
  float w0 = top_w[2 * t], w1 = top_w[2 * t + 1];
  size_t xo = (size_t)t * HD + lane * 8;
  float4 a = *(const float4*)(x + xo);
  float4 b = *(const float4*)(x + xo + 4);
  uint4 ya = *(const uint4*)(y2 + (size_t)(2 * t) * HD + lane * 8);
  uint4 yb = *(const uint4*)(y2 + (size_t)(2 * t + 1) * HD + lane * 8);
  float4 o0, o1;
  o0.x = a.x + w0 * bflo(ya.x) + w1 * bflo(yb.x);
  o0.y = a.y + w0 * bfhi(ya.x) + w1 * bfhi(yb.x);
  o0.z = a.z + w0 * bflo(ya.y) + w1 * bflo(yb.y);
  o0.w = a.w + w0 * bfhi(ya.y) + w1 * bfhi(yb.y);
  o1.x = b.x + w0 * bflo(ya.z) + w1 * bflo(yb.z);
  o1.y = b.y + w0 * bfhi(ya.z) + w1 * bfhi(yb.z);
  o1.z = b.z + w0 * bflo(ya.w) + w1 * bflo(yb.w);
  o1.w = b.w + w0 * bfhi(ya.w) + w1 * bfhi(yb.w);
  *(float4*)(out + xo) = o0;
  *(float4*)(out + xo + 4) = o1;
}

extern "C" void kernel_launch(void* const* d_in, const int* in_sizes, int n_in,
                              void* d_out, int out_size, void* d_ws, size_t ws_size,
                              hipStream_t stream) {
  const float* x  = (const float*)d_in[0];
  const float* Wg = (const float*)d_in[1];
  const float* bg = (const float*)d_in[2];
  const float* W1 = (const float*)d_in[3];
  const float* b1 = (const float*)d_in[4];
  const float* W2 = (const float*)d_in[5];
  const float* b2 = (const float*)d_in[6];
  float* out = (float*)d_out;

  char* w = (char*)d_ws;
  u32* counts   = (u32*)(w + 0);
  u32* pos_rel  = (u32*)(w + 32);
  float* Psum   = (float*)(w + 64);
  u32* padoff   = (u32*)(w + 96);
  int* perm_t   = (int*)(w + 256);                 // 135168 B
  int* top_e    = (int*)(w + 135424);              // 131072 B
  float* top_w  = (float*)(w + 266496);            // 131072 B
  u16* xb  = (u16*)(w + 397568);                   // 16 MB
  u16* W1T = (u16*)(w + 17174784);                 // 16 MB
  u16* W2T = (u16*)(w + 33952000);                 // 16 MB
  u16* h   = (u16*)(w + 50729216);                 // 132 MB
  u16* y2  = (u16*)(w + 189141248);                // 32 MB (token-major)
  if (ws_size < 224010496ull) return;   // loud validation fail

  (void)hipMemsetAsync(w, 0, 256, stream);             // ctrl
  k_prep<<<8192, 256, 0, stream>>>(W1, W1T, W2, W2T, x, Wg, bg,
                                   top_e, top_w, counts, Psum, xb);
  k_scatter<<<(BS_TOK * 2) / 256, 256, 0, stream>>>(top_e, top_w, counts, Psum,
                                                    pos_rel, perm_t, padoff, out);
  k_gemm<8, 8, IDIM, true, true, false><<<RT_MAX * 8, 512, 0, stream>>>(
      xb, HD, W1T, b1, perm_t, padoff, h);
  k_gemm<32, 2, HD, false, false, true><<<RT_MAX * 2, 512, 0, stream>>>(
      h, IDIM, W2T, b2, perm_t, padoff, y2);
  k_final<<<BS_TOK / 4, 256, 0, stream>>>(x, y2, top_w, out);
}

// Round 17
// 352.249 us; speedup vs baseline: 1.1242x; 1.1242x over previous
//
#include <hip/hip_runtime.h>

#define BS_TOK 16384
#define HD 512
#define IDIM 2048
#define NE 8
#define RT256 136             // max 256-row tiles after per-expert padding
#define RT128 (RT256 * 2)
#define CAP (RT256 * 256)     // 34816 slots

typedef unsigned short u16;
typedef unsigned int u32;
typedef unsigned long long u64;
typedef __attribute__((ext_vector_type(8))) __bf16 bf16x8;
typedef __attribute__((ext_vector_type(4))) float f32x4;

__device__ __forceinline__ u16 f2bf(float f) {
  u32 u = __builtin_bit_cast(u32, f);
  u += 0x7fffu + ((u >> 16) & 1u);
  return (u16)(u >> 16);
}
__device__ __forceinline__ u16 f2bf_hw(float f) {
  u32 r;
  asm("v_cvt_pk_bf16_f32 %0, %1, %2" : "=v"(r) : "v"(f), "v"(f));
  return (u16)r;
}
__device__ __forceinline__ u32 pack2bf(float a, float b) {
  u32 r;
  asm("v_cvt_pk_bf16_f32 %0, %1, %2" : "=v"(r) : "v"(a), "v"(b));
  return r;
}
__device__ __forceinline__ float bflo(u32 u) { return __builtin_bit_cast(float, u << 16); }
__device__ __forceinline__ float bfhi(u32 u) { return __builtin_bit_cast(float, u & 0xffff0000u); }
// gelu tanh-approx via sigmoid; exp via v_exp_f32 (=2^x), log2e folded. Saturation-safe.
__device__ __forceinline__ float gelu_t(float v) {
  float t = v * (-2.302558f - 0.1029474f * v * v);
  return v * __builtin_amdgcn_rcpf(1.0f + __builtin_amdgcn_exp2f(t));
}
__device__ __forceinline__ void gload16(const u16* g, u16* l) {
  __builtin_amdgcn_global_load_lds((const __attribute__((address_space(1))) u16*)g,
                                   (__attribute__((address_space(3))) u16*)l, 16, 0, 0);
}

// Fused prep: blocks [0,4096) = 64x64 weight transpose; [4096,8192) = router.
__global__ void k_prep(const float* __restrict__ W1, u16* __restrict__ W1T,
                       const float* __restrict__ W2, u16* __restrict__ W2T,
                       const float* __restrict__ x, const float* __restrict__ Wg,
                       const float* __restrict__ bg, int* __restrict__ top_e,
                       float* __restrict__ top_w, u32* __restrict__ counts,
                       float* __restrict__ Psum, u16* __restrict__ xb) {
  __shared__ float t[64][65];
  __shared__ float wg_s[HD * 9];
  __shared__ float Pp[NE];
  __shared__ u32 cnt[NE];
  int bid = blockIdx.x;
  int tid = threadIdx.x;
  if (bid < 4096) {
    int z = bid >> 8, tl = bid & 255;
    const float* in; u16* out; int Rin, Cin;
    if (z < NE) { in = W1; out = W1T; Rin = HD; Cin = IDIM; }
    else { in = W2; out = W2T; Rin = IDIM; Cin = HD; z -= NE; }
    size_t eb = (size_t)z * HD * IDIM;
    int tpr = Cin >> 6;
    int r0 = (tl / tpr) << 6, c0 = (tl % tpr) << 6;
    int row = tid >> 4, c4 = (tid & 15) << 2;
    #pragma unroll
    for (int i = 0; i < 4; ++i) {
      float4 v = *(const float4*)(in + eb + (size_t)(r0 + row + i * 16) * Cin + c0 + c4);
      t[row + i * 16][c4 + 0] = v.x; t[row + i * 16][c4 + 1] = v.y;
      t[row + i * 16][c4 + 2] = v.z; t[row + i * 16][c4 + 3] = v.w;
    }
    __syncthreads();
    int cc = tid >> 4, rr = (tid & 15) << 2;
    #pragma unroll
    for (int i = 0; i < 4; ++i) {
      int c = cc + i * 16;
      u32 lo = pack2bf(t[rr + 0][c], t[rr + 1][c]);
      u32 hi = pack2bf(t[rr + 2][c], t[rr + 3][c]);
      u64 v = (u64)lo | ((u64)hi << 32);
      *(u64*)(out + eb + (size_t)(c0 + c) * Rin + r0 + rr) = v;
    }
    return;
  }
  // ---- router ----
  if (tid < NE) { Pp[tid] = 0.f; cnt[tid] = 0; }
  for (int i = tid; i < HD * NE; i += 256) wg_s[(i >> 3) * 9 + (i & 7)] = Wg[i];
  __syncthreads();
  int wv = tid >> 6, lane = tid & 63;
  int tk = (bid - 4096) * 4 + wv;

  const float4* xr = (const float4*)(x + (size_t)tk * HD + lane * 8);
  float4 a = xr[0], b = xr[1];
  u32 p0 = pack2bf(a.x, a.y), p1 = pack2bf(a.z, a.w);
  u32 p2 = pack2bf(b.x, b.y), p3 = pack2bf(b.z, b.w);
  ((uint4*)(xb + (size_t)tk * HD))[lane] = make_uint4(p0, p1, p2, p3);

  float acc[NE];
  #pragma unroll
  for (int e = 0; e < NE; ++e) acc[e] = 0.f;
  #pragma unroll
  for (int j = 0; j < 8; ++j) {
    int h = lane + 64 * j;
    float xv = x[(size_t)tk * HD + h];
    const float* wrow = wg_s + h * 9;
    #pragma unroll
    for (int e = 0; e < NE; ++e) acc[e] += xv * wrow[e];
  }
  #pragma unroll
  for (int off = 32; off > 0; off >>= 1) {
    #pragma unroll
    for (int e = 0; e < NE; ++e) acc[e] += __shfl_down(acc[e], off);
  }
  if (lane == 0) {
    float lg[NE];
    #pragma unroll
    for (int e = 0; e < NE; ++e) lg[e] = acc[e] + bg[e];
    int i1 = 0; float m1 = lg[0];
    #pragma unroll
    for (int e = 1; e < NE; ++e) if (lg[e] > m1) { m1 = lg[e]; i1 = e; }
    int i2 = -1; float m2 = -1e30f;
    #pragma unroll
    for (int e = 0; e < NE; ++e) if (e != i1 && lg[e] > m2) { m2 = lg[e]; i2 = e; }
    float s = 0.f, p[NE];
    #pragma unroll
    for (int e = 0; e < NE; ++e) { p[e] = __expf(lg[e] - m1); s += p[e]; }
    float inv = 1.f / s;
    #pragma unroll
    for (int e = 0; e < NE; ++e) { p[e] *= inv; atomicAdd(&Pp[e], p[e]); }
    float denom = p[i1] + p[i2];
    top_e[2 * tk] = i1; top_e[2 * tk + 1] = i2;
    top_w[2 * tk] = p[i1] / denom; top_w[2 * tk + 1] = p[i2] / denom;
    atomicAdd(&cnt[i1], 1u); atomicAdd(&cnt[i2], 1u);
  }
  __syncthreads();
  if (tid < NE) { atomicAdd(&counts[tid], cnt[tid]); atomicAdd(&Psum[tid], Pp[tid]); }
}

// scatter with fused scan; 256-row padding; perm_t g=(token<<1)|k, pads -1.
__global__ void k_scatter(const int* __restrict__ top_e, const float* __restrict__ top_w,
                          const u32* __restrict__ counts, const float* __restrict__ Psum,
                          u32* __restrict__ pos_rel, int* __restrict__ perm_t,
                          u32* __restrict__ padoff, float* __restrict__ out) {
  __shared__ u32 po[NE];
  if (threadIdx.x == 0) {
    u32 off = 0; float loss = 0.f;
    for (int e = 0; e < NE; ++e) {
      po[e] = off;
      off += ((counts[e] + 255u) / 256u) * 256u;
      loss += ((float)counts[e] / (float)(BS_TOK * 2)) * (Psum[e] / (float)BS_TOK);
    }
    if (blockIdx.x == 0) {
      for (int e = 0; e < NE; ++e) padoff[e] = po[e];
      padoff[NE] = off;
      out[(size_t)BS_TOK * HD] = 0.01f * (float)NE * loss;
    }
  }
  __syncthreads();
  if (blockIdx.x == 0) {   // pad sentinels
    #pragma unroll
    for (int e = 0; e < NE; ++e) {
      u32 c = counts[e];
      u32 pc = ((c + 255u) / 256u) * 256u;
      for (u32 i = c + threadIdx.x; i < pc; i += 256) perm_t[po[e] + i] = -1;
    }
  }
  int g = blockIdx.x * 256 + threadIdx.x;
  int e = top_e[g];
  int lane = threadIdx.x & 63;
  #pragma unroll
  for (int ee = 0; ee < NE; ++ee) {
    unsigned long long m = __ballot(e == ee);
    if (e == ee) {
      int nb = __popcll(m & ((1ull << lane) - 1ull));
      int leader = __ffsll((unsigned long long)m) - 1;
      u32 base = 0;
      if (lane == leader) base = atomicAdd(&pos_rel[ee], (u32)__popcll(m));
      base = __shfl(base, leader);
      int slot = (int)(po[ee] + base) + nb;
      perm_t[slot] = g;
    }
  }
}

// GEMM1: 256x256 / BK=64, 512 thr / 8 waves (2M x 4N, wave tile 128x64).
// Faithful phase schedule with derived waits (counted vmcnt, no mid-loop drain):
//  P0: ds_read A-lo(8)+B-all(8); lgkm0+SB; s_barrier; 16 MFMA (fr0-3 x fc0-1)
//  P1: stage B(t+2) [B LDS read only in P0, sealed by P0 barrier]; 16 MFMA (fr0-3 x fc2-3)
//  P2: ds_read A-hi(8); lgkm0+SB; s_barrier [seals A]; 16 MFMA (fr4-7 x fc0-1)
//  P3: stage A(t+2); vmcnt(8) [8 outstanding = t+2's; older t+1 loads landed];
//      s_barrier; 16 MFMA (fr4-7 x fc2-3)
__global__ __launch_bounds__(512, 2) void k_gemm1(
    const u16* __restrict__ xb, const u16* __restrict__ W1T,
    const float* __restrict__ bias, const int* __restrict__ perm_t,
    const u32* __restrict__ padoff, u16* __restrict__ h) {
  __shared__ u16 As[2][16384], Bs[2][16384];   // 128 KB
  int nb = gridDim.x;                           // 1088
  int b = blockIdx.x;
  int tile = (b & 7) * (nb >> 3) + (b >> 3);    // XCD-chunked
  int rt = tile >> 3, ct = tile & 7;            // NCT=8
  u32 s0 = (u32)rt * 256u;
  if (s0 >= padoff[NE]) return;
  int e = 0;
  #pragma unroll
  for (int k = 1; k < NE; ++k) e += (s0 >= padoff[k]) ? 1 : 0;

  int tid = threadIdx.x;
  int wv = tid >> 6, lane = tid & 63;
  int l15 = lane & 15, lg4 = lane >> 4;
  int wm = wv >> 2, wn = wv & 3;

  // staging pointers: 4 A pieces + 4 B pieces per thread (rows (tid>>3)+i*64)
  const u16* apg[4]; const u16* bpg[4];
  #pragma unroll
  for (int i = 0; i < 4; ++i) {
    int row = (tid >> 3) + i * 64;
    int off = (((tid & 7) * 16) ^ ((row & 7) << 4)) >> 1;
    int g = perm_t[s0 + row];
    apg[i] = xb + (size_t)((g < 0 ? 0 : g) >> 1) * HD + off;
    bpg[i] = W1T + ((size_t)e * IDIM + ct * 256 + row) * HD + off;
  }

  int base_n = ct * 256 + wn * 64;
  f32x4 acc[8][4];
  #pragma unroll
  for (int fc = 0; fc < 4; ++fc) {
    float bv = bias[(size_t)e * IDIM + base_n + fc * 16 + l15];
    #pragma unroll
    for (int fr = 0; fr < 8; ++fr) acc[fr][fc] = f32x4{bv, bv, bv, bv};
  }

  // prologue: stage tiles 0 and 1 (8 loads each)
  #pragma unroll
  for (int i = 0; i < 4; ++i) gload16(apg[i], As[0] + tid * 8 + i * 4096);
  #pragma unroll
  for (int i = 0; i < 4; ++i) gload16(bpg[i], Bs[0] + tid * 8 + i * 4096);
  #pragma unroll
  for (int i = 0; i < 4; ++i) gload16(apg[i] + 64, As[1] + tid * 8 + i * 4096);
  #pragma unroll
  for (int i = 0; i < 4; ++i) gload16(bpg[i] + 64, Bs[1] + tid * 8 + i * 4096);
  asm volatile("s_waitcnt vmcnt(8)" ::: "memory");   // tile 0 landed
  __builtin_amdgcn_sched_barrier(0);
  __builtin_amdgcn_s_barrier();

  #define LDFRAG(BUF, ROW, KK) \
    *(const bf16x8*)((const char*)(BUF) + ((ROW) * 128 + (((KK) * 64 + lg4 * 16) ^ (((ROW) & 7) << 4))))

  for (int t = 0; t < 8; ++t) {
    int buf = t & 1;
    const u16* Ab = As[buf];
    const u16* Bb = Bs[buf];
    u16* Ad = As[buf];           // tile t+2 -> same buffer
    u16* Bd = Bs[buf];
    int k0 = (t + 2) * 64;
    bool pf = (t + 2) < 8;

    bf16x8 af[2][4], bfr[2][4];
    // ---- P0: A-lo + all B ----
    #pragma unroll
    for (int kk = 0; kk < 2; ++kk) {
      #pragma unroll
      for (int f = 0; f < 4; ++f) af[kk][f] = LDFRAG(Ab, wm * 128 + f * 16 + l15, kk);
      #pragma unroll
      for (int c = 0; c < 4; ++c) bfr[kk][c] = LDFRAG(Bb, wn * 64 + c * 16 + l15, kk);
    }
    asm volatile("s_waitcnt lgkmcnt(0)" ::: "memory");
    __builtin_amdgcn_sched_barrier(0);
    __builtin_amdgcn_s_barrier();            // seals A-lo + B reads
    __builtin_amdgcn_s_setprio(1);
    #pragma unroll
    for (int kk = 0; kk < 2; ++kk)
      #pragma unroll
      for (int f = 0; f < 4; ++f)
        #pragma unroll
        for (int c = 0; c < 2; ++c)
          acc[f][c] = __builtin_amdgcn_mfma_f32_16x16x32_bf16(af[kk][f], bfr[kk][c], acc[f][c], 0, 0, 0);
    __builtin_amdgcn_s_setprio(0);

    // ---- P1: stage B(t+2); MFMA fr0-3 x fc2-3 ----
    if (pf) {
      #pragma unroll
      for (int i = 0; i < 4; ++i) gload16(bpg[i] + k0, Bd + tid * 8 + i * 4096);
    }
    __builtin_amdgcn_s_setprio(1);
    #pragma unroll
    for (int kk = 0; kk < 2; ++kk)
      #pragma unroll
      for (int f = 0; f < 4; ++f)
        #pragma unroll
        for (int c = 2; c < 4; ++c)
          acc[f][c] = __builtin_amdgcn_mfma_f32_16x16x32_bf16(af[kk][f], bfr[kk][c], acc[f][c], 0, 0, 0);
    __builtin_amdgcn_s_setprio(0);

    // ---- P2: A-hi ----
    #pragma unroll
    for (int kk = 0; kk < 2; ++kk)
      #pragma unroll
      for (int f = 0; f < 4; ++f) af[kk][f] = LDFRAG(Ab, wm * 128 + 64 + f * 16 + l15, kk);
    asm volatile("s_waitcnt lgkmcnt(0)" ::: "memory");
    __builtin_amdgcn_sched_barrier(0);
    __builtin_amdgcn_s_barrier();            // seals A-hi reads
    __builtin_amdgcn_s_setprio(1);
    #pragma unroll
    for (int kk = 0; kk < 2; ++kk)
      #pragma unroll
      for (int f = 0; f < 4; ++f)
        #pragma unroll
        for (int c = 0; c < 2; ++c)
          acc[4 + f][c] = __builtin_amdgcn_mfma_f32_16x16x32_bf16(af[kk][f], bfr[kk][c], acc[4 + f][c], 0, 0, 0);
    __builtin_amdgcn_s_setprio(0);

    // ---- P3: stage A(t+2); gate; MFMA fr4-7 x fc2-3 ----
    if (pf) {
      #pragma unroll
      for (int i = 0; i < 4; ++i) gload16(apg[i] + k0, Ad + tid * 8 + i * 4096);
    }
    if (t + 1 < 8) {
      if (pf) asm volatile("s_waitcnt vmcnt(8)" ::: "memory");  // t+1 landed; t+2 in flight
      else    asm volatile("s_waitcnt vmcnt(0)" ::: "memory");  // tail drain
      __builtin_amdgcn_sched_barrier(0);
      __builtin_amdgcn_s_barrier();
    }
    __builtin_amdgcn_s_setprio(1);
    #pragma unroll
    for (int kk = 0; kk < 2; ++kk)
      #pragma unroll
      for (int f = 0; f < 4; ++f)
        #pragma unroll
        for (int c = 2; c < 4; ++c)
          acc[4 + f][c] = __builtin_amdgcn_mfma_f32_16x16x32_bf16(af[kk][f], bfr[kk][c], acc[4 + f][c], 0, 0, 0);
    __builtin_amdgcn_s_setprio(0);
  }
  #undef LDFRAG

  #pragma unroll
  for (int fr = 0; fr < 8; ++fr) {
    u32 mrow = s0 + wm * 128 + fr * 16 + lg4 * 4;
    #pragma unroll
    for (int rr = 0; rr < 4; ++rr) {
      #pragma unroll
      for (int fc = 0; fc < 4; ++fc) {
        float v = gelu_t(acc[fr][fc][rr]);   // bias already in acc
        h[(size_t)(mrow + rr) * IDIM + base_n + fc * 16 + l15] = f2bf_hw(v);
      }
    }
  }
}

// GEMM2: r15-proven 128x128 / BK=64 counted-vmcnt 2-phase, scatter epilogue.
template <int KSTEPS, int NCT, int NTOT>
__global__ __launch_bounds__(256, 2) void k_gemm2(
    const u16* __restrict__ A, int lda, const u16* __restrict__ W,
    const float* __restrict__ bias, const int* __restrict__ perm_t,
    const u32* __restrict__ padoff, u16* __restrict__ C) {
  __shared__ u16 As[2][8192], Bs[2][8192];
  int nb = gridDim.x;
  int b = blockIdx.x;
  int tile = (b & 7) * (nb >> 3) + (b >> 3);
  int rt = tile / NCT, ct = tile % NCT;
  u32 s0 = (u32)rt * 128u;
  if (s0 >= padoff[NE]) return;
  int e = 0;
  #pragma unroll
  for (int k = 1; k < NE; ++k) e += (s0 >= padoff[k]) ? 1 : 0;

  int tid = threadIdx.x;
  int wv = tid >> 6, lane = tid & 63;
  int l15 = lane & 15, lg4 = lane >> 4;
  int wr = wv >> 1, wc = wv & 1;

  int srow = tid >> 3;
  int cb = (tid & 7) * 16;
  int cbs = (cb ^ ((srow & 7) << 4)) >> 1;

  const u16* ap[4]; const u16* bp[4];
  #pragma unroll
  for (int i = 0; i < 4; ++i) {
    int r = i * 32 + srow;
    ap[i] = A + (size_t)(s0 + r) * lda + cbs;
    bp[i] = W + ((size_t)e * NTOT + ct * 128 + r) * (KSTEPS * 64) + cbs;
  }

  int base_n = ct * 128 + wc * 64;
  f32x4 acc[4][4];
  #pragma unroll
  for (int j = 0; j < 4; ++j) {
    float bv = bias[e * NTOT + base_n + j * 16 + l15];
    #pragma unroll
    for (int i = 0; i < 4; ++i) acc[i][j] = f32x4{bv, bv, bv, bv};
  }

  #pragma unroll
  for (int i = 0; i < 4; ++i) gload16(ap[i], As[0] + tid * 8 + i * 2048);
  #pragma unroll
  for (int i = 0; i < 4; ++i) gload16(bp[i], Bs[0] + tid * 8 + i * 2048);
  #pragma unroll
  for (int i = 0; i < 4; ++i) gload16(ap[i] + 64, As[1] + tid * 8 + i * 2048);
  #pragma unroll
  for (int i = 0; i < 4; ++i) gload16(bp[i] + 64, Bs[1] + tid * 8 + i * 2048);
  asm volatile("s_waitcnt vmcnt(8)" ::: "memory");
  __builtin_amdgcn_sched_barrier(0);
  __builtin_amdgcn_s_barrier();

  for (int ks = 0; ks < KSTEPS; ++ks) {
    int cur = ks & 1;
    const u16* Ab = As[cur];
    const u16* Bb = Bs[cur];
    bf16x8 af[2][4], bf[2][4];
    #pragma unroll
    for (int kk = 0; kk < 2; ++kk) {
      #pragma unroll
      for (int f = 0; f < 4; ++f) {
        int ra = wr * 64 + f * 16 + l15;
        af[kk][f] = *(const bf16x8*)((const char*)Ab +
                    (ra * 128 + ((kk * 64 + lg4 * 16) ^ ((ra & 7) << 4))));
        int rb = wc * 64 + f * 16 + l15;
        bf[kk][f] = *(const bf16x8*)((const char*)Bb +
                    (rb * 128 + ((kk * 64 + lg4 * 16) ^ ((rb & 7) << 4))));
      }
    }
    asm volatile("s_waitcnt lgkmcnt(0)" ::: "memory");
    __builtin_amdgcn_sched_barrier(0);
    __builtin_amdgcn_s_barrier();

    if (ks + 2 < KSTEPS) {
      int k0 = (ks + 2) * 64;
      #pragma unroll
      for (int i = 0; i < 4; ++i) gload16(ap[i] + k0, As[cur] + tid * 8 + i * 2048);
      #pragma unroll
      for (int i = 0; i < 4; ++i) gload16(bp[i] + k0, Bs[cur] + tid * 8 + i * 2048);
    }

    __builtin_amdgcn_s_setprio(1);
    #pragma unroll
    for (int kk = 0; kk < 2; ++kk)
      #pragma unroll
      for (int i = 0; i < 4; ++i)
        #pragma unroll
        for (int j = 0; j < 4; ++j)
          acc[i][j] = __builtin_amdgcn_mfma_f32_16x16x32_bf16(af[kk][i], bf[kk][j], acc[i][j], 0, 0, 0);
    __builtin_amdgcn_s_setprio(0);

    if (ks + 1 < KSTEPS) {
      if (ks + 2 < KSTEPS) {
        asm volatile("s_waitcnt vmcnt(8)" ::: "memory");
      } else {
        asm volatile("s_waitcnt vmcnt(0)" ::: "memory");
      }
      __builtin_amdgcn_sched_barrier(0);
      __builtin_amdgcn_s_barrier();
    }
  }

  #pragma unroll
  for (int i = 0; i < 4; ++i) {
    u32 mrow = s0 + wr * 64 + i * 16 + lg4 * 4;
    #pragma unroll
    for (int rr = 0; rr < 4; ++rr) {
      int g = perm_t[mrow + rr];
      if (g >= 0) {
        #pragma unroll
        for (int j = 0; j < 4; ++j)
          C[(size_t)g * NTOT + base_n + j * 16 + l15] = f2bf_hw(acc[i][j][rr]);
      }
    }
  }
}

// Fully-streaming final: out[t] = x[t] + w0*y2[2t] + w1*y2[2t+1]
__global__ void k_final(const float* __restrict__ x, const u16* __restrict__ y2,
                        const float* __restrict__ top_w, float* __restrict__ out) {
  int tid = threadIdx.x;
  int t = blockIdx.x * 4 + (tid >> 6);
  int lane = tid & 63;
  float w0 = top_w[2 * t], w1 = top_w[2 * t + 1];
  size_t xo = (size_t)t * HD + lane * 8;
  float4 a = *(const float4*)(x + xo);
  float4 b = *(const float4*)(x + xo + 4);
  uint4 ya = *(const uint4*)(y2 + (size_t)(2 * t) * HD + lane * 8);
  uint4 yb = *(const uint4*)(y2 + (size_t)(2 * t + 1) * HD + lane * 8);
  float4 o0, o1;
  o0.x = a.x + w0 * bflo(ya.x) + w1 * bflo(yb.x);
  o0.y = a.y + w0 * bfhi(ya.x) + w1 * bfhi(yb.x);
  o0.z = a.z + w0 * bflo(ya.y) + w1 * bflo(yb.y);
  o0.w = a.w + w0 * bfhi(ya.y) + w1 * bfhi(yb.y);
  o1.x = b.x + w0 * bflo(ya.z) + w1 * bflo(yb.z);
  o1.y = b.y + w0 * bfhi(ya.z) + w1 * bfhi(yb.z);
  o1.z = b.z + w0 * bflo(ya.w) + w1 * bflo(yb.w);
  o1.w = b.w + w0 * bfhi(ya.w) + w1 * bfhi(yb.w);
  *(float4*)(out + xo) = o0;
  *(float4*)(out + xo + 4) = o1;
}

extern "C" void kernel_launch(void* const* d_in, const int* in_sizes, int n_in,
                              void* d_out, int out_size, void* d_ws, size_t ws_size,
                              hipStream_t stream) {
  const float* x  = (const float*)d_in[0];
  const float* Wg = (const float*)d_in[1];
  const float* bg = (const float*)d_in[2];
  const float* W1 = (const float*)d_in[3];
  const float* b1 = (const float*)d_in[4];
  const float* W2 = (const float*)d_in[5];
  const float* b2 = (const float*)d_in[6];
  float* out = (float*)d_out;

  char* w = (char*)d_ws;
  u32* counts   = (u32*)(w + 0);
  u32* pos_rel  = (u32*)(w + 32);
  float* Psum   = (float*)(w + 64);
  u32* padoff   = (u32*)(w + 96);
  int* perm_t   = (int*)(w + 256);                 // 139264 B (CAP ints)
  int* top_e    = (int*)(w + 139520);              // 131072 B
  float* top_w  = (float*)(w + 270592);            // 131072 B
  u16* xb  = (u16*)(w + 401664);                   // 16 MB
  u16* W1T = (u16*)(w + 17178880);                 // 16 MB
  u16* W2T = (u16*)(w + 33956096);                 // 16 MB
  u16* h   = (u16*)(w + 50733312);                 // 136 MB (CAP x 2048 bf16)
  u16* y2  = xb;   // alias: xb/W1T dead after GEMM1; y2 = 32 MB fits xb+W1T
  if (ws_size < 193339648ull) return;   // loud validation fail

  (void)hipMemsetAsync(w, 0, 256, stream);             // ctrl
  k_prep<<<8192, 256, 0, stream>>>(W1, W1T, W2, W2T, x, Wg, bg,
                                   top_e, top_w, counts, Psum, xb);
  k_scatter<<<(BS_TOK * 2) / 256, 256, 0, stream>>>(top_e, top_w, counts, Psum,
                                                    pos_rel, perm_t, padoff, out);
  k_gemm1<<<RT256 * 8, 512, 0, stream>>>(xb, W1T, b1, perm_t, padoff, h);
  k_gemm2<32, 4, HD><<<RT128 * 4, 256, 0, stream>>>(h, IDIM, W2T, b2, perm_t, padoff, y2);
  k_final<<<BS_TOK / 4, 256, 0, stream>>>(x, y2, top_w, out);
}

// Round 18
// 343.277 us; speedup vs baseline: 1.1536x; 1.0261x over previous
//
#include <hip/hip_runtime.h>

#define BS_TOK 16384
#define HD 512
#define IDIM 2048
#define NE 8
#define RT_MAX 264            // max 128-row tiles after per-expert padding
#define CAP (RT_MAX * 128)    // 33792 slots

typedef unsigned short u16;
typedef unsigned int u32;
typedef unsigned long long u64;
typedef __attribute__((ext_vector_type(8))) __bf16 bf16x8;
typedef __attribute__((ext_vector_type(4))) float f32x4;

__device__ __forceinline__ u16 f2bf(float f) {
  u32 u = __builtin_bit_cast(u32, f);
  u += 0x7fffu + ((u >> 16) & 1u);
  return (u16)(u >> 16);
}
__device__ __forceinline__ u16 f2bf_hw(float f) {
  u32 r;
  asm("v_cvt_pk_bf16_f32 %0, %1, %2" : "=v"(r) : "v"(f), "v"(f));
  return (u16)r;
}
__device__ __forceinline__ u32 pack2bf(float a, float b) {
  u32 r;
  asm("v_cvt_pk_bf16_f32 %0, %1, %2" : "=v"(r) : "v"(a), "v"(b));
  return r;
}
__device__ __forceinline__ float bflo(u32 u) { return __builtin_bit_cast(float, u << 16); }
__device__ __forceinline__ float bfhi(u32 u) { return __builtin_bit_cast(float, u & 0xffff0000u); }
// gelu tanh-approx via sigmoid; exp via v_exp_f32 (=2^x), log2e folded. Saturation-safe.
__device__ __forceinline__ float gelu_t(float v) {
  float t = v * (-2.302558f - 0.1029474f * v * v);
  return v * __builtin_amdgcn_rcpf(1.0f + __builtin_amdgcn_exp2f(t));
}
__device__ __forceinline__ void gload16(const u16* g, u16* l) {
  __builtin_amdgcn_global_load_lds((const __attribute__((address_space(1))) u16*)g,
                                   (__attribute__((address_space(3))) u16*)l, 16, 0, 0);
}

// Fused prep: blocks [0,4096) = 64x64 weight transpose (u64 coalesced stores);
// blocks [4096,8192) = router (padded-LDS, conflict-free), 4 tokens/block.
__global__ void k_prep(const float* __restrict__ W1, u16* __restrict__ W1T,
                       const float* __restrict__ W2, u16* __restrict__ W2T,
                       const float* __restrict__ x, const float* __restrict__ Wg,
                       const float* __restrict__ bg, int* __restrict__ top_e,
                       float* __restrict__ top_w, u32* __restrict__ counts,
                       float* __restrict__ Psum, u16* __restrict__ xb) {
  __shared__ float t[64][65];
  __shared__ float wg_s[HD * 9];
  __shared__ float Pp[NE];
  __shared__ u32 cnt[NE];
  int bid = blockIdx.x;
  int tid = threadIdx.x;
  if (bid < 4096) {
    int z = bid >> 8, tl = bid & 255;
    const float* in; u16* out; int Rin, Cin;
    if (z < NE) { in = W1; out = W1T; Rin = HD; Cin = IDIM; }
    else { in = W2; out = W2T; Rin = IDIM; Cin = HD; z -= NE; }
    size_t eb = (size_t)z * HD * IDIM;
    int tpr = Cin >> 6;
    int r0 = (tl / tpr) << 6, c0 = (tl % tpr) << 6;
    int row = tid >> 4, c4 = (tid & 15) << 2;
    #pragma unroll
    for (int i = 0; i < 4; ++i) {
      float4 v = *(const float4*)(in + eb + (size_t)(r0 + row + i * 16) * Cin + c0 + c4);
      t[row + i * 16][c4 + 0] = v.x; t[row + i * 16][c4 + 1] = v.y;
      t[row + i * 16][c4 + 2] = v.z; t[row + i * 16][c4 + 3] = v.w;
    }
    __syncthreads();
    int cc = tid >> 4, rr = (tid & 15) << 2;
    #pragma unroll
    for (int i = 0; i < 4; ++i) {
      int c = cc + i * 16;
      u32 lo = pack2bf(t[rr + 0][c], t[rr + 1][c]);
      u32 hi = pack2bf(t[rr + 2][c], t[rr + 3][c]);
      u64 v = (u64)lo | ((u64)hi << 32);
      *(u64*)(out + eb + (size_t)(c0 + c) * Rin + r0 + rr) = v;   // 8B coalesced
    }
    return;
  }
  // ---- router ----
  if (tid < NE) { Pp[tid] = 0.f; cnt[tid] = 0; }
  for (int i = tid; i < HD * NE; i += 256) wg_s[(i >> 3) * 9 + (i & 7)] = Wg[i];
  __syncthreads();
  int wv = tid >> 6, lane = tid & 63;
  int tk = (bid - 4096) * 4 + wv;

  const float4* xr = (const float4*)(x + (size_t)tk * HD + lane * 8);
  float4 a = xr[0], b = xr[1];
  u32 p0 = pack2bf(a.x, a.y), p1 = pack2bf(a.z, a.w);
  u32 p2 = pack2bf(b.x, b.y), p3 = pack2bf(b.z, b.w);
  ((uint4*)(xb + (size_t)tk * HD))[lane] = make_uint4(p0, p1, p2, p3);

  float acc[NE];
  #pragma unroll
  for (int e = 0; e < NE; ++e) acc[e] = 0.f;
  #pragma unroll
  for (int j = 0; j < 8; ++j) {
    int h = lane + 64 * j;
    float xv = x[(size_t)tk * HD + h];
    const float* wrow = wg_s + h * 9;
    #pragma unroll
    for (int e = 0; e < NE; ++e) acc[e] += xv * wrow[e];
  }
  #pragma unroll
  for (int off = 32; off > 0; off >>= 1) {
    #pragma unroll
    for (int e = 0; e < NE; ++e) acc[e] += __shfl_down(acc[e], off);
  }
  if (lane == 0) {
    float lg[NE];
    #pragma unroll
    for (int e = 0; e < NE; ++e) lg[e] = acc[e] + bg[e];
    int i1 = 0; float m1 = lg[0];
    #pragma unroll
    for (int e = 1; e < NE; ++e) if (lg[e] > m1) { m1 = lg[e]; i1 = e; }
    int i2 = -1; float m2 = -1e30f;
    #pragma unroll
    for (int e = 0; e < NE; ++e) if (e != i1 && lg[e] > m2) { m2 = lg[e]; i2 = e; }
    float s = 0.f, p[NE];
    #pragma unroll
    for (int e = 0; e < NE; ++e) { p[e] = __expf(lg[e] - m1); s += p[e]; }
    float inv = 1.f / s;
    #pragma unroll
    for (int e = 0; e < NE; ++e) { p[e] *= inv; atomicAdd(&Pp[e], p[e]); }
    float denom = p[i1] + p[i2];
    top_e[2 * tk] = i1; top_e[2 * tk + 1] = i2;
    top_w[2 * tk] = p[i1] / denom; top_w[2 * tk + 1] = p[i2] / denom;
    atomicAdd(&cnt[i1], 1u); atomicAdd(&cnt[i2], 1u);
  }
  __syncthreads();
  if (tid < NE) { atomicAdd(&counts[tid], cnt[tid]); atomicAdd(&Psum[tid], Pp[tid]); }
}

// scatter with fused scan; perm_t stores g = (token<<1)|k (pads stay -1 sentinel).
__global__ void k_scatter(const int* __restrict__ top_e, const float* __restrict__ top_w,
                          const u32* __restrict__ counts, const float* __restrict__ Psum,
                          u32* __restrict__ pos_rel, int* __restrict__ perm_t,
                          u32* __restrict__ padoff, float* __restrict__ out) {
  __shared__ u32 po[NE];
  if (threadIdx.x == 0) {
    u32 off = 0; float loss = 0.f;
    for (int e = 0; e < NE; ++e) {
      po[e] = off;
      off += ((counts[e] + 127u) / 128u) * 128u;
      loss += ((float)counts[e] / (float)(BS_TOK * 2)) * (Psum[e] / (float)BS_TOK);
    }
    if (blockIdx.x == 0) {
      for (int e = 0; e < NE; ++e) padoff[e] = po[e];
      padoff[NE] = off;
      out[(size_t)BS_TOK * HD] = 0.01f * (float)NE * loss;
    }
  }
  __syncthreads();
  int g = blockIdx.x * 256 + threadIdx.x;   // (token,k) pair id
  int e = top_e[g];
  int lane = threadIdx.x & 63;
  #pragma unroll
  for (int ee = 0; ee < NE; ++ee) {
    unsigned long long m = __ballot(e == ee);
    if (e == ee) {
      int nb = __popcll(m & ((1ull << lane) - 1ull));
      int leader = __ffsll((unsigned long long)m) - 1;
      u32 base = 0;
      if (lane == leader) base = atomicAdd(&pos_rel[ee], (u32)__popcll(m));
      base = __shfl(base, leader);
      int slot = (int)(po[ee] + base) + nb;
      perm_t[slot] = g;
    }
  }
}

// 128x128 / BK=64 GEMM, counted-vmcnt 2-phase (proven r9/r12/r15 skeleton).
// GATHER: A row = token from perm_t g>>1 (pads clamp to 0).
// SCAT:   epilogue scatters rows to C[g*NTOT] (pads g<0 skipped).
template <int KSTEPS, int NCT, int NTOT, bool GATHER, bool ACT, bool SCAT>
__global__ __launch_bounds__(256, 2) void k_gemm(
    const u16* __restrict__ A, int lda, const u16* __restrict__ W,
    const float* __restrict__ bias, const int* __restrict__ perm_t,
    const u32* __restrict__ padoff, u16* __restrict__ C) {
  __shared__ u16 As[2][8192], Bs[2][8192];
  int nb = gridDim.x;
  int b = blockIdx.x;
  int tile = (b & 7) * (nb >> 3) + (b >> 3);   // XCD-chunked (nb % 8 == 0)
  int rt = tile / NCT, ct = tile % NCT;
  u32 s0 = (u32)rt * 128u;
  if (s0 >= padoff[NE]) return;
  int e = 0;
  #pragma unroll
  for (int k = 1; k < NE; ++k) e += (s0 >= padoff[k]) ? 1 : 0;

  int tid = threadIdx.x;
  int wv = tid >> 6, lane = tid & 63;
  int l15 = lane & 15, lg4 = lane >> 4;
  int wr = wv >> 1, wc = wv & 1;

  int srow = tid >> 3;
  int cb = (tid & 7) * 16;
  int cbs = (cb ^ ((srow & 7) << 4)) >> 1;     // pre-swizzled source elem offset

  const u16* ap[4]; const u16* bp[4];
  #pragma unroll
  for (int i = 0; i < 4; ++i) {
    int r = i * 32 + srow;
    int arow;
    if (GATHER) {
      int g = perm_t[s0 + r];
      arow = (g < 0 ? 0 : g) >> 1;
    } else {
      arow = (int)(s0 + r);
    }
    ap[i] = A + (size_t)arow * lda + cbs;
    bp[i] = W + ((size_t)e * NTOT + ct * 128 + r) * (KSTEPS * 64) + cbs;
  }

  int base_n = ct * 128 + wc * 64;
  f32x4 acc[4][4];
  #pragma unroll
  for (int j = 0; j < 4; ++j) {
    float bv = bias[e * NTOT + base_n + j * 16 + l15];
    #pragma unroll
    for (int i = 0; i < 4; ++i) acc[i][j] = f32x4{bv, bv, bv, bv};
  }

  // prologue: stage K-steps 0 and 1 (16 loads in flight)
  #pragma unroll
  for (int i = 0; i < 4; ++i) gload16(ap[i], As[0] + tid * 8 + i * 2048);
  #pragma unroll
  for (int i = 0; i < 4; ++i) gload16(bp[i], Bs[0] + tid * 8 + i * 2048);
  #pragma unroll
  for (int i = 0; i < 4; ++i) gload16(ap[i] + 64, As[1] + tid * 8 + i * 2048);
  #pragma unroll
  for (int i = 0; i < 4; ++i) gload16(bp[i] + 64, Bs[1] + tid * 8 + i * 2048);
  asm volatile("s_waitcnt vmcnt(8)" ::: "memory");
  __builtin_amdgcn_sched_barrier(0);
  __builtin_amdgcn_s_barrier();

  for (int ks = 0; ks < KSTEPS; ++ks) {
    int cur = ks & 1;
    const u16* Ab = As[cur];
    const u16* Bb = Bs[cur];
    bf16x8 af[2][4], bf[2][4];
    #pragma unroll
    for (int kk = 0; kk < 2; ++kk) {
      #pragma unroll
      for (int f = 0; f < 4; ++f) {
        int ra = wr * 64 + f * 16 + l15;
        af[kk][f] = *(const bf16x8*)((const char*)Ab +
                    (ra * 128 + ((kk * 64 + lg4 * 16) ^ ((ra & 7) << 4))));
        int rb = wc * 64 + f * 16 + l15;
        bf[kk][f] = *(const bf16x8*)((const char*)Bb +
                    (rb * 128 + ((kk * 64 + lg4 * 16) ^ ((rb & 7) << 4))));
      }
    }
    asm volatile("s_waitcnt lgkmcnt(0)" ::: "memory");
    __builtin_amdgcn_sched_barrier(0);                   // rule #18 fence
    __builtin_amdgcn_s_barrier();

    if (ks + 2 < KSTEPS) {
      int k0 = (ks + 2) * 64;
      #pragma unroll
      for (int i = 0; i < 4; ++i) gload16(ap[i] + k0, As[cur] + tid * 8 + i * 2048);
      #pragma unroll
      for (int i = 0; i < 4; ++i) gload16(bp[i] + k0, Bs[cur] + tid * 8 + i * 2048);
    }

    __builtin_amdgcn_s_setprio(1);
    #pragma unroll
    for (int kk = 0; kk < 2; ++kk)
      #pragma unroll
      for (int i = 0; i < 4; ++i)
        #pragma unroll
        for (int j = 0; j < 4; ++j)
          acc[i][j] = __builtin_amdgcn_mfma_f32_16x16x32_bf16(af[kk][i], bf[kk][j], acc[i][j], 0, 0, 0);
    __builtin_amdgcn_s_setprio(0);

    if (ks + 1 < KSTEPS) {
      if (ks + 2 < KSTEPS) {
        asm volatile("s_waitcnt vmcnt(8)" ::: "memory");
      } else {
        asm volatile("s_waitcnt vmcnt(0)" ::: "memory");
      }
      __builtin_amdgcn_sched_barrier(0);
      __builtin_amdgcn_s_barrier();
    }
  }

  #pragma unroll
  for (int i = 0; i < 4; ++i) {
    u32 mrow = s0 + wr * 64 + i * 16 + lg4 * 4;
    #pragma unroll
    for (int rr = 0; rr < 4; ++rr) {
      u32 m = mrow + rr;
      if (SCAT) {
        int g = perm_t[m];
        if (g >= 0) {
          #pragma unroll
          for (int j = 0; j < 4; ++j)
            C[(size_t)g * NTOT + base_n + j * 16 + l15] = f2bf_hw(acc[i][j][rr]);
        }
      } else {
        #pragma unroll
        for (int j = 0; j < 4; ++j) {
          float v = acc[i][j][rr];
          if (ACT) v = gelu_t(v);
          C[(size_t)m * NTOT + base_n + j * 16 + l15] = f2bf_hw(v);
        }
      }
    }
  }
}

// Fully-streaming final: out[t] = x[t] + w0*y2[2t] + w1*y2[2t+1]  (no gather)
__global__ void k_final(const float* __restrict__ x, const u16* __restrict__ y2,
                        const float* __restrict__ top_w, float* __restrict__ out) {
  int tid = threadIdx.x;
  int t = blockIdx.x * 4 + (tid >> 6);
  int lane = tid & 63;
  float w0 = top_w[2 * t], w1 = top_w[2 * t + 1];
  size_t xo = (size_t)t * HD + lane * 8;
  float4 a = *(const float4*)(x + xo);
  float4 b = *(const float4*)(x + xo + 4);
  uint4 ya = *(const uint4*)(y2 + (size_t)(2 * t) * HD + lane * 8);
  uint4 yb = *(const uint4*)(y2 + (size_t)(2 * t + 1) * HD + lane * 8);
  float4 o0, o1;
  o0.x = a.x + w0 * bflo(ya.x) + w1 * bflo(yb.x);
  o0.y = a.y + w0 * bfhi(ya.x) + w1 * bfhi(yb.x);
  o0.z = a.z + w0 * bflo(ya.y) + w1 * bflo(yb.y);
  o0.w = a.w + w0 * bfhi(ya.y) + w1 * bfhi(yb.y);
  o1.x = b.x + w0 * bflo(ya.z) + w1 * bflo(yb.z);
  o1.y = b.y + w0 * bfhi(ya.z) + w1 * bfhi(yb.z);
  o1.z = b.z + w0 * bflo(ya.w) + w1 * bflo(yb.w);
  o1.w = b.w + w0 * bfhi(ya.w) + w1 * bfhi(yb.w);
  *(float4*)(out + xo) = o0;
  *(float4*)(out + xo + 4) = o1;
}

extern "C" void kernel_launch(void* const* d_in, const int* in_sizes, int n_in,
                              void* d_out, int out_size, void* d_ws, size_t ws_size,
                              hipStream_t stream) {
  const float* x  = (const float*)d_in[0];
  const float* Wg = (const float*)d_in[1];
  const float* bg = (const float*)d_in[2];
  const float* W1 = (const float*)d_in[3];
  const float* b1 = (const float*)d_in[4];
  const float* W2 = (const float*)d_in[5];
  const float* b2 = (const float*)d_in[6];
  float* out = (float*)d_out;

  char* w = (char*)d_ws;
  u32* counts   = (u32*)(w + 0);
  u32* pos_rel  = (u32*)(w + 32);
  float* Psum   = (float*)(w + 64);
  u32* padoff   = (u32*)(w + 96);
  int* perm_t   = (int*)(w + 256);                 // 135168 B (0xFF sentinel)
  int* top_e    = (int*)(w + 135424);              // 131072 B
  float* top_w  = (float*)(w + 266496);            // 131072 B
  u16* xb  = (u16*)(w + 397568);                   // 16 MB
  u16* W1T = (u16*)(w + 17174784);                 // 16 MB
  u16* W2T = (u16*)(w + 33952000);                 // 16 MB
  u16* h   = (u16*)(w + 50729216);                 // 132 MB
  u16* y2  = (u16*)(w + 189141248);                // 32 MB (token-major)
  if (ws_size < 224010496ull) return;   // loud validation fail

  (void)hipMemsetAsync(w, 0, 256, stream);             // ctrl
  (void)hipMemsetAsync(w + 256, 0xFF, 135168, stream); // perm_t -> -1 sentinel
  k_prep<<<8192, 256, 0, stream>>>(W1, W1T, W2, W2T, x, Wg, bg,
                                   top_e, top_w, counts, Psum, xb);
  k_scatter<<<(BS_TOK * 2) / 256, 256, 0, stream>>>(top_e, top_w, counts, Psum,
                                                    pos_rel, perm_t, padoff, out);
  k_gemm<8, 16, IDIM, true, true, false><<<RT_MAX * 16, 256, 0, stream>>>(
      xb, HD, W1T, b1, perm_t, padoff, h);
  k_gemm<32, 4, HD, false, false, true><<<RT_MAX * 4, 256, 0, stream>>>(
      h, IDIM, W2T, b2, perm_t, padoff, y2);
  k_final<<<BS_TOK / 4, 256, 0, stream>>>(x, y2, top_w, out);
}

// Round 19
// 342.377 us; speedup vs baseline: 1.1566x; 1.0026x over previous
//
#include <hip/hip_runtime.h>

#define BS_TOK 16384
#define HD 512
#define IDIM 2048
#define NE 8
#define RT_MAX 264            // max 128-row tiles after per-expert padding
#define CAP (RT_MAX * 128)    // 33792 slots

typedef unsigned short u16;
typedef unsigned int u32;
typedef unsigned long long u64;
typedef __attribute__((ext_vector_type(8))) __bf16 bf16x8;
typedef __attribute__((ext_vector_type(4))) float f32x4;

__device__ __forceinline__ u16 f2bf(float f) {
  u32 u = __builtin_bit_cast(u32, f);
  u += 0x7fffu + ((u >> 16) & 1u);
  return (u16)(u >> 16);
}
__device__ __forceinline__ u16 f2bf_hw(float f) {
  u32 r;
  asm("v_cvt_pk_bf16_f32 %0, %1, %2" : "=v"(r) : "v"(f), "v"(f));
  return (u16)r;
}
__device__ __forceinline__ u32 pack2bf(float a, float b) {
  u32 r;
  asm("v_cvt_pk_bf16_f32 %0, %1, %2" : "=v"(r) : "v"(a), "v"(b));
  return r;
}
__device__ __forceinline__ float bflo(u32 u) { return __builtin_bit_cast(float, u << 16); }
__device__ __forceinline__ float bfhi(u32 u) { return __builtin_bit_cast(float, u & 0xffff0000u); }
// gelu tanh-approx via sigmoid; exp via v_exp_f32 (=2^x), log2e folded. Saturation-safe.
__device__ __forceinline__ float gelu_t(float v) {
  float t = v * (-2.302558f - 0.1029474f * v * v);
  return v * __builtin_amdgcn_rcpf(1.0f + __builtin_amdgcn_exp2f(t));
}
__device__ __forceinline__ void gload16(const u16* g, u16* l) {
  __builtin_amdgcn_global_load_lds((const __attribute__((address_space(1))) u16*)g,
                                   (__attribute__((address_space(3))) u16*)l, 16, 0, 0);
}

// Fused prep: blocks [0,4096) = 64x64 weight transpose (u64 coalesced stores);
// blocks [4096,8192) = router (padded-LDS, conflict-free), 4 tokens/block.
__global__ void k_prep(const float* __restrict__ W1, u16* __restrict__ W1T,
                       const float* __restrict__ W2, u16* __restrict__ W2T,
                       const float* __restrict__ x, const float* __restrict__ Wg,
                       const float* __restrict__ bg, int* __restrict__ top_e,
                       float* __restrict__ top_w, u32* __restrict__ counts,
                       float* __restrict__ Psum, u16* __restrict__ xb) {
  __shared__ float t[64][65];
  __shared__ float wg_s[HD * 9];
  __shared__ float Pp[NE];
  __shared__ u32 cnt[NE];
  int bid = blockIdx.x;
  int tid = threadIdx.x;
  if (bid < 4096) {
    int z = bid >> 8, tl = bid & 255;
    const float* in; u16* out; int Rin, Cin;
    if (z < NE) { in = W1; out = W1T; Rin = HD; Cin = IDIM; }
    else { in = W2; out = W2T; Rin = IDIM; Cin = HD; z -= NE; }
    size_t eb = (size_t)z * HD * IDIM;
    int tpr = Cin >> 6;
    int r0 = (tl / tpr) << 6, c0 = (tl % tpr) << 6;
    int row = tid >> 4, c4 = (tid & 15) << 2;
    #pragma unroll
    for (int i = 0; i < 4; ++i) {
      float4 v = *(const float4*)(in + eb + (size_t)(r0 + row + i * 16) * Cin + c0 + c4);
      t[row + i * 16][c4 + 0] = v.x; t[row + i * 16][c4 + 1] = v.y;
      t[row + i * 16][c4 + 2] = v.z; t[row + i * 16][c4 + 3] = v.w;
    }
    __syncthreads();
    int cc = tid >> 4, rr = (tid & 15) << 2;
    #pragma unroll
    for (int i = 0; i < 4; ++i) {
      int c = cc + i * 16;
      u32 lo = pack2bf(t[rr + 0][c], t[rr + 1][c]);
      u32 hi = pack2bf(t[rr + 2][c], t[rr + 3][c]);
      u64 v = (u64)lo | ((u64)hi << 32);
      *(u64*)(out + eb + (size_t)(c0 + c) * Rin + r0 + rr) = v;   // 8B coalesced
    }
    return;
  }
  // ---- router ----
  if (tid < NE) { Pp[tid] = 0.f; cnt[tid] = 0; }
  for (int i = tid; i < HD * NE; i += 256) wg_s[(i >> 3) * 9 + (i & 7)] = Wg[i];
  __syncthreads();
  int wv = tid >> 6, lane = tid & 63;
  int tk = (bid - 4096) * 4 + wv;

  const float4* xr = (const float4*)(x + (size_t)tk * HD + lane * 8);
  float4 a = xr[0], b = xr[1];
  u32 p0 = pack2bf(a.x, a.y), p1 = pack2bf(a.z, a.w);
  u32 p2 = pack2bf(b.x, b.y), p3 = pack2bf(b.z, b.w);
  ((uint4*)(xb + (size_t)tk * HD))[lane] = make_uint4(p0, p1, p2, p3);

  float acc[NE];
  #pragma unroll
  for (int e = 0; e < NE; ++e) acc[e] = 0.f;
  #pragma unroll
  for (int j = 0; j < 8; ++j) {
    int h = lane + 64 * j;
    float xv = x[(size_t)tk * HD + h];
    const float* wrow = wg_s + h * 9;
    #pragma unroll
    for (int e = 0; e < NE; ++e) acc[e] += xv * wrow[e];
  }
  #pragma unroll
  for (int off = 32; off > 0; off >>= 1) {
    #pragma unroll
    for (int e = 0; e < NE; ++e) acc[e] += __shfl_down(acc[e], off);
  }
  if (lane == 0) {
    float lg[NE];
    #pragma unroll
    for (int e = 0; e < NE; ++e) lg[e] = acc[e] + bg[e];
    int i1 = 0; float m1 = lg[0];
    #pragma unroll
    for (int e = 1; e < NE; ++e) if (lg[e] > m1) { m1 = lg[e]; i1 = e; }
    int i2 = -1; float m2 = -1e30f;
    #pragma unroll
    for (int e = 0; e < NE; ++e) if (e != i1 && lg[e] > m2) { m2 = lg[e]; i2 = e; }
    float s = 0.f, p[NE];
    #pragma unroll
    for (int e = 0; e < NE; ++e) { p[e] = __expf(lg[e] - m1); s += p[e]; }
    float inv = 1.f / s;
    #pragma unroll
    for (int e = 0; e < NE; ++e) { p[e] *= inv; atomicAdd(&Pp[e], p[e]); }
    float denom = p[i1] + p[i2];
    top_e[2 * tk] = i1; top_e[2 * tk + 1] = i2;
    top_w[2 * tk] = p[i1] / denom; top_w[2 * tk + 1] = p[i2] / denom;
    atomicAdd(&cnt[i1], 1u); atomicAdd(&cnt[i2], 1u);
  }
  __syncthreads();
  if (tid < NE) { atomicAdd(&counts[tid], cnt[tid]); atomicAdd(&Psum[tid], Pp[tid]); }
}

// scatter with fused scan; perm_t stores g = (token<<1)|k; block 0 writes the
// -1 pad sentinels (disjoint from occupied slots; r16-validated) + padoff + loss.
__global__ void k_scatter(const int* __restrict__ top_e, const float* __restrict__ top_w,
                          const u32* __restrict__ counts, const float* __restrict__ Psum,
                          u32* __restrict__ pos_rel, int* __restrict__ perm_t,
                          u32* __restrict__ padoff, float* __restrict__ out) {
  __shared__ u32 po[NE];
  if (threadIdx.x == 0) {
    u32 off = 0; float loss = 0.f;
    for (int e = 0; e < NE; ++e) {
      po[e] = off;
      off += ((counts[e] + 127u) / 128u) * 128u;
      loss += ((float)counts[e] / (float)(BS_TOK * 2)) * (Psum[e] / (float)BS_TOK);
    }
    if (blockIdx.x == 0) {
      for (int e = 0; e < NE; ++e) padoff[e] = po[e];
      padoff[NE] = off;
      out[(size_t)BS_TOK * HD] = 0.01f * (float)NE * loss;
    }
  }
  __syncthreads();
  if (blockIdx.x == 0) {   // pad sentinels (slots >= counts[e] are never scattered to)
    #pragma unroll
    for (int e = 0; e < NE; ++e) {
      u32 c = counts[e];
      u32 pc = ((c + 127u) / 128u) * 128u;
      for (u32 i = c + threadIdx.x; i < pc; i += 256) perm_t[po[e] + i] = -1;
    }
  }
  int g = blockIdx.x * 256 + threadIdx.x;   // (token,k) pair id
  int e = top_e[g];
  int lane = threadIdx.x & 63;
  #pragma unroll
  for (int ee = 0; ee < NE; ++ee) {
    unsigned long long m = __ballot(e == ee);
    if (e == ee) {
      int nb = __popcll(m & ((1ull << lane) - 1ull));
      int leader = __ffsll((unsigned long long)m) - 1;
      u32 base = 0;
      if (lane == leader) base = atomicAdd(&pos_rel[ee], (u32)__popcll(m));
      base = __shfl(base, leader);
      int slot = (int)(po[ee] + base) + nb;
      perm_t[slot] = g;
    }
  }
}

// 128x128 / BK=64 GEMM, counted-vmcnt 2-phase (proven r9/r12/r15/r18 skeleton).
// GATHER: A row = token from perm_t g>>1 (pads clamp to 0).
// SCAT:   epilogue scatters rows to C[g*NTOT] (pads g<0 skipped).
template <int KSTEPS, int NCT, int NTOT, bool GATHER, bool ACT, bool SCAT>
__global__ __launch_bounds__(256, 2) void k_gemm(
    const u16* __restrict__ A, int lda, const u16* __restrict__ W,
    const float* __restrict__ bias, const int* __restrict__ perm_t,
    const u32* __restrict__ padoff, u16* __restrict__ C) {
  __shared__ u16 As[2][8192], Bs[2][8192];
  int nb = gridDim.x;
  int b = blockIdx.x;
  int tile = (b & 7) * (nb >> 3) + (b >> 3);   // XCD-chunked (nb % 8 == 0)
  int rt = tile / NCT, ct = tile % NCT;
  u32 s0 = (u32)rt * 128u;
  if (s0 >= padoff[NE]) return;
  int e = 0;
  #pragma unroll
  for (int k = 1; k < NE; ++k) e += (s0 >= padoff[k]) ? 1 : 0;

  int tid = threadIdx.x;
  int wv = tid >> 6, lane = tid & 63;
  int l15 = lane & 15, lg4 = lane >> 4;
  int wr = wv >> 1, wc = wv & 1;

  int srow = tid >> 3;
  int cb = (tid & 7) * 16;
  int cbs = (cb ^ ((srow & 7) << 4)) >> 1;     // pre-swizzled source elem offset

  const u16* ap[4]; const u16* bp[4];
  #pragma unroll
  for (int i = 0; i < 4; ++i) {
    int r = i * 32 + srow;
    int arow;
    if (GATHER) {
      int g = perm_t[s0 + r];
      arow = (g < 0 ? 0 : g) >> 1;
    } else {
      arow = (int)(s0 + r);
    }
    ap[i] = A + (size_t)arow * lda + cbs;
    bp[i] = W + ((size_t)e * NTOT + ct * 128 + r) * (KSTEPS * 64) + cbs;
  }

  int base_n = ct * 128 + wc * 64;
  f32x4 acc[4][4];
  #pragma unroll
  for (int j = 0; j < 4; ++j) {
    float bv = bias[e * NTOT + base_n + j * 16 + l15];
    #pragma unroll
    for (int i = 0; i < 4; ++i) acc[i][j] = f32x4{bv, bv, bv, bv};
  }

  // prologue: stage K-steps 0 and 1 (16 loads in flight)
  #pragma unroll
  for (int i = 0; i < 4; ++i) gload16(ap[i], As[0] + tid * 8 + i * 2048);
  #pragma unroll
  for (int i = 0; i < 4; ++i) gload16(bp[i], Bs[0] + tid * 8 + i * 2048);
  #pragma unroll
  for (int i = 0; i < 4; ++i) gload16(ap[i] + 64, As[1] + tid * 8 + i * 2048);
  #pragma unroll
  for (int i = 0; i < 4; ++i) gload16(bp[i] + 64, Bs[1] + tid * 8 + i * 2048);
  asm volatile("s_waitcnt vmcnt(8)" ::: "memory");
  __builtin_amdgcn_sched_barrier(0);
  __builtin_amdgcn_s_barrier();

  for (int ks = 0; ks < KSTEPS; ++ks) {
    int cur = ks & 1;
    const u16* Ab = As[cur];
    const u16* Bb = Bs[cur];
    bf16x8 af[2][4], bf[2][4];
    #pragma unroll
    for (int kk = 0; kk < 2; ++kk) {
      #pragma unroll
      for (int f = 0; f < 4; ++f) {
        int ra = wr * 64 + f * 16 + l15;
        af[kk][f] = *(const bf16x8*)((const char*)Ab +
                    (ra * 128 + ((kk * 64 + lg4 * 16) ^ ((ra & 7) << 4))));
        int rb = wc * 64 + f * 16 + l15;
        bf[kk][f] = *(const bf16x8*)((const char*)Bb +
                    (rb * 128 + ((kk * 64 + lg4 * 16) ^ ((rb & 7) << 4))));
      }
    }
    asm volatile("s_waitcnt lgkmcnt(0)" ::: "memory");
    __builtin_amdgcn_sched_barrier(0);                   // rule #18 fence
    __builtin_amdgcn_s_barrier();

    if (ks + 2 < KSTEPS) {
      int k0 = (ks + 2) * 64;
      #pragma unroll
      for (int i = 0; i < 4; ++i) gload16(ap[i] + k0, As[cur] + tid * 8 + i * 2048);
      #pragma unroll
      for (int i = 0; i < 4; ++i) gload16(bp[i] + k0, Bs[cur] + tid * 8 + i * 2048);
    }

    __builtin_amdgcn_s_setprio(1);
    #pragma unroll
    for (int kk = 0; kk < 2; ++kk)
      #pragma unroll
      for (int i = 0; i < 4; ++i)
        #pragma unroll
        for (int j = 0; j < 4; ++j)
          acc[i][j] = __builtin_amdgcn_mfma_f32_16x16x32_bf16(af[kk][i], bf[kk][j], acc[i][j], 0, 0, 0);
    __builtin_amdgcn_s_setprio(0);

    if (ks + 1 < KSTEPS) {
      if (ks + 2 < KSTEPS) {
        asm volatile("s_waitcnt vmcnt(8)" ::: "memory");
      } else {
        asm volatile("s_waitcnt vmcnt(0)" ::: "memory");
      }
      __builtin_amdgcn_sched_barrier(0);
      __builtin_amdgcn_s_barrier();
    }
  }

  #pragma unroll
  for (int i = 0; i < 4; ++i) {
    u32 mrow = s0 + wr * 64 + i * 16 + lg4 * 4;
    #pragma unroll
    for (int rr = 0; rr < 4; ++rr) {
      u32 m = mrow + rr;
      if (SCAT) {
        int g = perm_t[m];
        if (g >= 0) {
          #pragma unroll
          for (int j = 0; j < 4; ++j)
            C[(size_t)g * NTOT + base_n + j * 16 + l15] = f2bf_hw(acc[i][j][rr]);
        }
      } else {
        #pragma unroll
        for (int j = 0; j < 4; ++j) {
          float v = acc[i][j][rr];
          if (ACT) v = gelu_t(v);
          C[(size_t)m * NTOT + base_n + j * 16 + l15] = f2bf_hw(v);
        }
      }
    }
  }
}

// Fully-streaming final: out[t] = x[t] + w0*y2[2t] + w1*y2[2t+1]  (no gather)
__global__ void k_final(const float* __restrict__ x, const u16* __restrict__ y2,
                        const float* __restrict__ top_w, float* __restrict__ out) {
  int tid = threadIdx.x;
  int t = blockIdx.x * 4 + (tid >> 6);
  int lane = tid & 63;
  float w0 = top_w[2 * t], w1 = top_w[2 * t + 1];
  size_t xo = (size_t)t * HD + lane * 8;
  float4 a = *(const float4*)(x + xo);
  float4 b = *(const float4*)(x + xo + 4);
  uint4 ya = *(const uint4*)(y2 + (size_t)(2 * t) * HD + lane * 8);
  uint4 yb = *(const uint4*)(y2 + (size_t)(2 * t + 1) * HD + lane * 8);
  float4 o0, o1;
  o0.x = a.x + w0 * bflo(ya.x) + w1 * bflo(yb.x);
  o0.y = a.y + w0 * bfhi(ya.x) + w1 * bfhi(yb.x);
  o0.z = a.z + w0 * bflo(ya.y) + w1 * bflo(yb.y);
  o0.w = a.w + w0 * bfhi(ya.y) + w1 * bfhi(yb.y);
  o1.x = b.x + w0 * bflo(ya.z) + w1 * bflo(yb.z);
  o1.y = b.y + w0 * bfhi(ya.z) + w1 * bfhi(yb.z);
  o1.z = b.z + w0 * bflo(ya.w) + w1 * bflo(yb.w);
  o1.w = b.w + w0 * bfhi(ya.w) + w1 * bfhi(yb.w);
  *(float4*)(out + xo) = o0;
  *(float4*)(out + xo + 4) = o1;
}

extern "C" void kernel_launch(void* const* d_in, const int* in_sizes, int n_in,
                              void* d_out, int out_size, void* d_ws, size_t ws_size,
                              hipStream_t stream) {
  const float* x  = (const float*)d_in[0];
  const float* Wg = (const float*)d_in[1];
  const float* bg = (const float*)d_in[2];
  const float* W1 = (const float*)d_in[3];
  const float* b1 = (const float*)d_in[4];
  const float* W2 = (const float*)d_in[5];
  const float* b2 = (const float*)d_in[6];
  float* out = (float*)d_out;

  char* w = (char*)d_ws;
  u32* counts   = (u32*)(w + 0);
  u32* pos_rel  = (u32*)(w + 32);
  float* Psum   = (float*)(w + 64);
  u32* padoff   = (u32*)(w + 96);
  int* perm_t   = (int*)(w + 256);                 // 135168 B
  int* top_e    = (int*)(w + 135424);              // 131072 B
  float* top_w  = (float*)(w + 266496);            // 131072 B
  u16* xb  = (u16*)(w + 397568);                   // 16 MB
  u16* W1T = (u16*)(w + 17174784);                 // 16 MB
  u16* W2T = (u16*)(w + 33952000);                 // 16 MB
  u16* h   = (u16*)(w + 50729216);                 // 132 MB
  u16* y2  = (u16*)(w + 189141248);                // 32 MB (token-major)
  if (ws_size < 224010496ull) return;   // loud validation fail

  (void)hipMemsetAsync(w, 0, 256, stream);             // ctrl words only
  k_prep<<<8192, 256, 0, stream>>>(W1, W1T, W2, W2T, x, Wg, bg,
                                   top_e, top_w, counts, Psum, xb);
  k_scatter<<<(BS_TOK * 2) / 256, 256, 0, stream>>>(top_e, top_w, counts, Psum,
                                                    pos_rel, perm_t, padoff, out);
  k_gemm<8, 16, IDIM, true, true, false><<<RT_MAX * 16, 256, 0, stream>>>(
      xb, HD, W1T, b1, perm_t, padoff, h);
  k_gemm<32, 4, HD, false, false, true><<<RT_MAX * 4, 256, 0, stream>>>(
      h, IDIM, W2T, b2, perm_t, padoff, y2);
  k_final<<<BS_TOK / 4, 256, 0, stream>>>(x, y2, top_w, out);
}